// Round 1
// 395.190 us; speedup vs baseline: 1.1402x; 1.1402x over previous
//
#include <hip/hip_runtime.h>
#include <hip/hip_bf16.h>

#define NN 100000
#define EE 1600000
#define DOUT 40
#define LN_EPS 1e-5f
#define NB 391     // (NN+255)/256 node blocks
#define NBUCK 391  // buckets of 256 dst nodes
#define TILE 2048
#define TBLK 782   // ceil(EE/TILE)
#define BCAP 8192  // per-bucket capacity (expected 4092 +- 64, no padding)

typedef __attribute__((ext_vector_type(8))) short short8;   // 8 bf16 = 4 VGPRs
typedef __attribute__((ext_vector_type(4))) float f32x4;    // MFMA acc

// ---------------------------------------------------------------- bf16 helpers (RNE pack)
__device__ __forceinline__ float blo(unsigned u) { return __uint_as_float(u << 16); }
__device__ __forceinline__ float bhi(unsigned u) { return __uint_as_float(u & 0xffff0000u); }
__device__ __forceinline__ unsigned bpack(float lo, float hi) {
    unsigned a = __float_as_uint(lo);
    unsigned b = __float_as_uint(hi);
    a = (a + 0x7fffu + ((a >> 16) & 1u)) >> 16;
    b = (b + 0x7fffu + ((b >> 16) & 1u)) & 0xffff0000u;
    return (a & 0xffffu) | b;
}

// ---------------------------------------------------------------- bucket build
__global__ void binit_k(int* __restrict__ bucketCur) {
    int b = blockIdx.x * 256 + threadIdx.x;
    if (b < NBUCK) bucketCur[b] = b * BCAP;
}

// 782 blocks x 512 threads x 4 edges. NO global degree atomics (degree is
// derived per-bucket in reorder2_k). Pass 1: per-wave LDS histogram.
// One global atomic per nonzero bucket per block. Pass 2: scatter into
// fixed-capacity bucket regions, per-wave sub-chunks (contiguous writes).
__global__ __launch_bounds__(512, 8) void bucket_k(const int* __restrict__ src,
                                                   const int* __restrict__ dst,
                                                   int* __restrict__ bucketCur,
                                                   unsigned* __restrict__ bE) {
    __shared__ int cnt[8][NBUCK];
    __shared__ int basew[8][NBUCK];
    int tid = threadIdx.x;
    int wv = tid >> 6;
    for (int i = tid; i < 8 * NBUCK; i += 512) ((int*)cnt)[i] = 0;
    __syncthreads();
    long e0 = (long)blockIdx.x * TILE;
    int d[4];
#pragma unroll
    for (int i = 0; i < 4; ++i) {
        long e = e0 + tid + i * 512;
        d[i] = (e < EE) ? dst[e] : -1;
    }
#pragma unroll
    for (int i = 0; i < 4; ++i) {
        if (d[i] >= 0) atomicAdd(&cnt[wv][d[i] >> 8], 1);
    }
    __syncthreads();
    for (int b = tid; b < NBUCK; b += 512) {
        int c[8];
        int tot = 0;
#pragma unroll
        for (int w = 0; w < 8; ++w) { c[w] = cnt[w][b]; tot += c[w]; }
        int base = tot ? atomicAdd(&bucketCur[b], tot) : 0;
        int run = base;
#pragma unroll
        for (int w = 0; w < 8; ++w) { basew[w][b] = run; run += c[w]; cnt[w][b] = 0; }
    }
    __syncthreads();
#pragma unroll
    for (int i = 0; i < 4; ++i) {
        if (d[i] >= 0) {
            long e = e0 + tid + i * 512;
            int b = d[i] >> 8;
            int pos = basew[wv][b] + atomicAdd(&cnt[wv][b], 1);
            bE[pos] = (unsigned)src[e] | ((unsigned)(d[i] & 255) << 24);
        }
    }
}

// ---------------------------------------------------------------- bucket -> exact CSR + degI + cursor + dinv
// One block per bucket. Bucket prefix computed in-block via LDS scan of
// exact bucket totals (bucketCur[b] - b*BCAP). Per-node degrees via a
// 256-entry LDS histogram; CSR writes stay in one ~16KB window.
__global__ __launch_bounds__(512, 4) void reorder2_k(const int* __restrict__ bucketCur,
                                                     const unsigned* __restrict__ bE,
                                                     int* __restrict__ csrSrc,
                                                     int* __restrict__ degI,
                                                     int* __restrict__ cursor,
                                                     float* __restrict__ dinv) {
    __shared__ int sScan[512];
    __shared__ int sHist[256];
    __shared__ int sPre[256];
    __shared__ int sStart[256];
    int tid = threadIdx.x;
    int b = blockIdx.x;
    // --- exclusive prefix of bucket totals (391 values, 512-wide scan)
    int c = (tid < NBUCK) ? (bucketCur[tid] - tid * BCAP) : 0;
    sScan[tid] = c;
    __syncthreads();
    for (int off = 1; off < 512; off <<= 1) {
        int t = (tid >= off) ? sScan[tid - off] : 0;
        __syncthreads();
        sScan[tid] += t;
        __syncthreads();
    }
    int bbase = (b == 0) ? 0 : sScan[b - 1];   // LDS broadcast
    // --- per-node histogram of this bucket
    if (tid < 256) sHist[tid] = 0;
    __syncthreads();
    int start = b * BCAP;
    int end = bucketCur[b];
    for (int e = start + tid; e < end; e += 512) {
        unsigned v = bE[e];
        atomicAdd(&sHist[v >> 24], 1);
    }
    __syncthreads();
    // --- inclusive scan over 256 node counts
    if (tid < 256) sPre[tid] = sHist[tid];
    __syncthreads();
    for (int off = 1; off < 256; off <<= 1) {
        int t = (tid >= off && tid < 256) ? sPre[tid - off] : 0;
        __syncthreads();
        if (tid < 256) sPre[tid] += t;
        __syncthreads();
    }
    if (tid < 256) {
        int h = sHist[tid];
        int excl = sPre[tid] - h;
        int st = bbase + excl;
        sStart[tid] = st;
        int nd = (b << 8) + tid;
        if (nd < NN) {
            degI[nd] = h;
            cursor[nd] = st;
            dinv[nd] = rsqrtf((float)h + 1.0f);
        }
    }
    __syncthreads();
    // --- scatter into exact CSR
    for (int e = start + tid; e < end; e += 512) {
        unsigned v = bE[e];
        int pos = atomicAdd(&sStart[v >> 24], 1);
        csrSrc[pos] = (int)(v & 0xFFFFFFu);
    }
}

// ---------------------------------------------------------------- MFMA GEMM: H' = bf16((X@W)*dinv)
template <int K>
__global__ __launch_bounds__(256, 2) void gemm_mfma(const float* __restrict__ X,
                                                    const float* __restrict__ W,
                                                    const float* __restrict__ dinv,
                                                    unsigned* __restrict__ H) {
    constexpr int C = K / 32;
    __shared__ unsigned short sW16[K * 66];
    __shared__ float sD[64 * 65];
    int tid = threadIdx.x;
    for (int i = tid; i < K * 64; i += 256) {
        int k = i >> 6, n = i & 63;
        sW16[k * 66 + n] = (unsigned short)(bpack(W[i], 0.f) & 0xffffu);
    }
    __syncthreads();
    int wv = tid >> 6, lane = tid & 63;
    int q = lane >> 4, ln = lane & 15;
    short8 bfrag[C][4];
#pragma unroll
    for (int c = 0; c < C; ++c) {
#pragma unroll
        for (int t = 0; t < 4; ++t) {
            int kb = (c * 32 + q * 8) * 66 + t * 16 + ln;
            unsigned u0 = (unsigned)sW16[kb]       | ((unsigned)sW16[kb + 66]  << 16);
            unsigned u1 = (unsigned)sW16[kb + 132] | ((unsigned)sW16[kb + 198] << 16);
            unsigned u2 = (unsigned)sW16[kb + 264] | ((unsigned)sW16[kb + 330] << 16);
            unsigned u3 = (unsigned)sW16[kb + 396] | ((unsigned)sW16[kb + 462] << 16);
            uint4 u = make_uint4(u0, u1, u2, u3);
            bfrag[c][t] = __builtin_bit_cast(short8, u);
        }
    }
    int base = blockIdx.x * 64;
    int node = base + wv * 16 + ln;
    bool ok = node < NN;
    short8 afrag[C];
#pragma unroll
    for (int c = 0; c < C; ++c) {
        float4 f0 = make_float4(0.f, 0.f, 0.f, 0.f);
        float4 f1 = make_float4(0.f, 0.f, 0.f, 0.f);
        if (ok) {
            const float4* xp = (const float4*)(X + (long)node * K + c * 32 + q * 8);
            f0 = xp[0];
            f1 = xp[1];
        }
        uint4 u;
        u.x = bpack(f0.x, f0.y);
        u.y = bpack(f0.z, f0.w);
        u.z = bpack(f1.x, f1.y);
        u.w = bpack(f1.z, f1.w);
        afrag[c] = __builtin_bit_cast(short8, u);
    }
#pragma unroll
    for (int t = 0; t < 4; ++t) {
        f32x4 acc = {0.f, 0.f, 0.f, 0.f};
#pragma unroll
        for (int c = 0; c < C; ++c)
            acc = __builtin_amdgcn_mfma_f32_16x16x32_bf16(afrag[c], bfrag[c][t], acc, 0, 0, 0);
#pragma unroll
        for (int r = 0; r < 4; ++r)
            sD[(wv * 16 + q * 4 + r) * 65 + t * 16 + ln] = acc[r];
    }
    __syncthreads();
    for (int i = tid; i < 64 * 32; i += 256) {
        int row = i >> 5, c2 = i & 31;
        int nd = base + row;
        if (nd < NN) {
            float di = dinv[nd];
            float lo = sD[row * 65 + c2 * 2] * di;
            float hi = sD[row * 65 + c2 * 2 + 1] * di;
            H[nd * 32 + c2] = bpack(lo, hi);
        }
    }
}

// ---------------------------------------------------------------- aggregate + bias + relu + optional LN (proven clean)
__global__ __launch_bounds__(256, 4) void agg_k(
        const int* __restrict__ cursor, const int* __restrict__ degI,
        const int* __restrict__ csrSrc, const float* __restrict__ dinv,
        const uint2* __restrict__ H2, const float4* __restrict__ bias4,
        const float4* __restrict__ g4, const float4* __restrict__ beta4,
        float4* __restrict__ OUT4, int doLN) {
    int tid = threadIdx.x;
    int w = tid >> 6, lane = tid & 63;
    int g = lane >> 4;
    int f = lane & 15;
    int node = blockIdx.x * 4 + w;
    int start = cursor[node];
    int end = start + degI[node];
    float ax = 0.f, ay = 0.f, az = 0.f, aw = 0.f;
    float bx = 0.f, by = 0.f, bz = 0.f, bw = 0.f;
    int e = start + g;
    for (; e + 4 < end; e += 8) {
        int s0 = csrSrc[e];
        int s1 = csrSrc[e + 4];
        uint2 q0 = H2[(long)s0 * 16 + f];
        uint2 q1 = H2[(long)s1 * 16 + f];
        ax += blo(q0.x); ay += bhi(q0.x); az += blo(q0.y); aw += bhi(q0.y);
        bx += blo(q1.x); by += bhi(q1.x); bz += blo(q1.y); bw += bhi(q1.y);
    }
    if (e < end) {
        uint2 q0 = H2[(long)csrSrc[e] * 16 + f];
        ax += blo(q0.x); ay += bhi(q0.x); az += blo(q0.y); aw += bhi(q0.y);
    }
    ax += bx; ay += by; az += bz; aw += bw;
    ax += __shfl_xor(ax, 16); ay += __shfl_xor(ay, 16);
    az += __shfl_xor(az, 16); aw += __shfl_xor(aw, 16);
    ax += __shfl_xor(ax, 32); ay += __shfl_xor(ay, 32);
    az += __shfl_xor(az, 32); aw += __shfl_xor(aw, 32);
    float di = dinv[node];
    uint2 qs = H2[(long)node * 16 + f];
    float4 bb = bias4[f];
    float vx = fmaxf((ax + blo(qs.x)) * di + bb.x, 0.f);
    float vy = fmaxf((ay + bhi(qs.x)) * di + bb.y, 0.f);
    float vz = fmaxf((az + blo(qs.y)) * di + bb.z, 0.f);
    float vw = fmaxf((aw + bhi(qs.y)) * di + bb.w, 0.f);
    if (doLN) {
        float s = vx + vy + vz + vw;
        s += __shfl_xor(s, 1); s += __shfl_xor(s, 2);
        s += __shfl_xor(s, 4); s += __shfl_xor(s, 8);
        float mu = s * (1.f / 64.f);
        vx -= mu; vy -= mu; vz -= mu; vw -= mu;
        float vs = vx * vx + vy * vy + vz * vz + vw * vw;
        vs += __shfl_xor(vs, 1); vs += __shfl_xor(vs, 2);
        vs += __shfl_xor(vs, 4); vs += __shfl_xor(vs, 8);
        float inv = rsqrtf(vs * (1.f / 64.f) + LN_EPS);
        float4 gg = g4[f];
        float4 tt = beta4[f];
        vx = vx * inv * gg.x + tt.x;
        vy = vy * inv * gg.y + tt.y;
        vz = vz * inv * gg.z + tt.z;
        vw = vw * inv * gg.w + tt.w;
    }
    if (g == 0) OUT4[(long)node * 16 + f] = make_float4(vx, vy, vz, vw);
}

// ---------------------------------------------------------------- fuse the two head linears
__global__ void fuse_k(const float* __restrict__ W0, const float* __restrict__ b0,
                       const float* __restrict__ W1, const float* __restrict__ b1,
                       float* __restrict__ Wf, float* __restrict__ bf) {
    int tid = threadIdx.x;
    for (int i = tid; i < 64 * 48; i += 256) {
        int k = i / 48, n = i % 48;
        float acc = 0.f;
        if (n < DOUT) {
            for (int j = 0; j < 64; ++j) acc = fmaf(W0[k * 64 + j], W1[j * DOUT + n], acc);
        }
        Wf[i] = acc;
    }
    for (int n = tid; n < 48; n += 256) {
        float acc = 0.f;
        if (n < DOUT) {
            acc = b1[n];
            for (int j = 0; j < 64; ++j) acc = fmaf(b0[j], W1[j * DOUT + n], acc);
        }
        bf[n] = acc;
    }
}

// ---------------------------------------------------------------- MLP head via MFMA: OUT = Hin @ Wf + bf
__global__ __launch_bounds__(256, 2) void mlp_mfma(const float* __restrict__ Hin,
                                                   const float* __restrict__ Wf,
                                                   const float* __restrict__ bf,
                                                   float* __restrict__ OUT) {
    __shared__ unsigned short sW16[64 * 50];
    int tid = threadIdx.x;
    for (int i = tid; i < 64 * 48; i += 256) {
        int k = i / 48, n = i % 48;
        sW16[k * 50 + n] = (unsigned short)(bpack(Wf[i], 0.f) & 0xffffu);
    }
    __syncthreads();
    int wv = tid >> 6, lane = tid & 63;
    int q = lane >> 4, ln = lane & 15;
    short8 bfrag[2][3];
#pragma unroll
    for (int c = 0; c < 2; ++c) {
#pragma unroll
        for (int t = 0; t < 3; ++t) {
            int kb = (c * 32 + q * 8) * 50 + t * 16 + ln;
            unsigned u0 = (unsigned)sW16[kb]       | ((unsigned)sW16[kb + 50]  << 16);
            unsigned u1 = (unsigned)sW16[kb + 100] | ((unsigned)sW16[kb + 150] << 16);
            unsigned u2 = (unsigned)sW16[kb + 200] | ((unsigned)sW16[kb + 250] << 16);
            unsigned u3 = (unsigned)sW16[kb + 300] | ((unsigned)sW16[kb + 350] << 16);
            uint4 u = make_uint4(u0, u1, u2, u3);
            bfrag[c][t] = __builtin_bit_cast(short8, u);
        }
    }
    int base = blockIdx.x * 64;
    int node = base + wv * 16 + ln;
    bool ok = node < NN;
    short8 afrag[2];
#pragma unroll
    for (int c = 0; c < 2; ++c) {
        float4 f0 = make_float4(0.f, 0.f, 0.f, 0.f);
        float4 f1 = make_float4(0.f, 0.f, 0.f, 0.f);
        if (ok) {
            const float4* xp = (const float4*)(Hin + (long)node * 64 + c * 32 + q * 8);
            f0 = xp[0];
            f1 = xp[1];
        }
        uint4 u;
        u.x = bpack(f0.x, f0.y);
        u.y = bpack(f0.z, f0.w);
        u.z = bpack(f1.x, f1.y);
        u.w = bpack(f1.z, f1.w);
        afrag[c] = __builtin_bit_cast(short8, u);
    }
#pragma unroll
    for (int t = 0; t < 3; ++t) {
        f32x4 acc = {0.f, 0.f, 0.f, 0.f};
        acc = __builtin_amdgcn_mfma_f32_16x16x32_bf16(afrag[0], bfrag[0][t], acc, 0, 0, 0);
        acc = __builtin_amdgcn_mfma_f32_16x16x32_bf16(afrag[1], bfrag[1][t], acc, 0, 0, 0);
        int col = t * 16 + ln;
        if (col < DOUT) {
            float bv = bf[col];
#pragma unroll
            for (int r = 0; r < 4; ++r) {
                int nd = base + wv * 16 + q * 4 + r;
                if (nd < NN) OUT[(long)nd * DOUT + col] = acc[r] + bv;
            }
        }
    }
}

// ----------------------------------------------------------------
extern "C" void kernel_launch(void* const* d_in, const int* in_sizes, int n_in,
                              void* d_out, int out_size, void* d_ws, size_t ws_size,
                              hipStream_t stream) {
    const float* x    = (const float*)d_in[0];
    const int*   ei   = (const int*)d_in[1];
    const int*   srcI = ei;
    const int*   dstI = ei + EE;
    const float* W0   = (const float*)d_in[2];
    const float* b0   = (const float*)d_in[3];
    const float* W1   = (const float*)d_in[4];
    const float* b1   = (const float*)d_in[5];
    const float* W2   = (const float*)d_in[6];
    const float* b2   = (const float*)d_in[7];
    const float* ln0g = (const float*)d_in[8];
    const float* ln0b = (const float*)d_in[9];
    const float* ln1g = (const float*)d_in[10];
    const float* ln1b = (const float*)d_in[11];
    const float* mpW0 = (const float*)d_in[12];
    const float* mpb0 = (const float*)d_in[13];
    const float* mpW1 = (const float*)d_in[14];
    const float* mpb1 = (const float*)d_in[15];
    float* out = (float*)d_out;

    char* ws = (char*)d_ws;
    float*    dinv      = (float*)   (ws + 0);                      // 400 KB
    int*      degI      = (int*)     (ws + 512l * 1024);            // 400 KB
    int*      cursor    = (int*)     (ws + 1024l * 1024);           // 400 KB
    int*      bucketCur = (int*)     (ws + 1600l * 1024);
    float*    Wf        = (float*)   (ws + 1792l * 1024);
    float*    bfv       = (float*)   (ws + 1984l * 1024);
    unsigned* bE        = (unsigned*)(ws + 2048l * 1024);           // 391*8192*4 = 12.8 MB
    int*      csrSrc    = (int*)     (ws + 15l * 1024 * 1024);      // 6.4 MB
    unsigned* bufA      = (unsigned*)(ws + 22l * 1024 * 1024);      // bf16 H' 12.8 MB
    float*    bufB      = (float*)   (ws + 35l * 1024 * 1024);      // f32 hidden 25.6 MB

    const int aggBlocks  = NN / 4;             // 25000 exact
    const int gemmBlocks = (NN + 63) / 64;     // 1563

    binit_k<<<2, 256, 0, stream>>>(bucketCur);
    bucket_k<<<TBLK, 512, 0, stream>>>(srcI, dstI, bucketCur, bE);
    reorder2_k<<<NBUCK, 512, 0, stream>>>(bucketCur, bE, csrSrc, degI, cursor, dinv);
    fuse_k<<<1, 256, 0, stream>>>(mpW0, mpb0, mpW1, mpb1, Wf, bfv);

    // layer 0
    gemm_mfma<128><<<gemmBlocks, 256, 0, stream>>>(x, W0, dinv, bufA);
    agg_k<<<aggBlocks, 256, 0, stream>>>(cursor, degI, csrSrc, dinv, (const uint2*)bufA,
                                         (const float4*)b0, (const float4*)ln0g,
                                         (const float4*)ln0b, (float4*)bufB, 1);
    // layer 1
    gemm_mfma<64><<<gemmBlocks, 256, 0, stream>>>(bufB, W1, dinv, bufA);
    agg_k<<<aggBlocks, 256, 0, stream>>>(cursor, degI, csrSrc, dinv, (const uint2*)bufA,
                                         (const float4*)b1, (const float4*)ln1g,
                                         (const float4*)ln1b, (float4*)bufB, 1);
    // layer 2 (no LN) then fused MLP head via MFMA
    gemm_mfma<64><<<gemmBlocks, 256, 0, stream>>>(bufB, W2, dinv, bufA);
    agg_k<<<aggBlocks, 256, 0, stream>>>(cursor, degI, csrSrc, dinv, (const uint2*)bufA,
                                         (const float4*)b2, (const float4*)ln0g,
                                         (const float4*)ln0b, (float4*)bufB, 0);
    mlp_mfma<<<gemmBlocks, 256, 0, stream>>>(bufB, Wf, bfv, out);
}